// Round 1
// 3348.359 us; speedup vs baseline: 1.0875x; 1.0875x over previous
//
#include <hip/hip_runtime.h>

// Problem constants (B,S,D=16,2048,256; K codebooks=8, CD=1024)
#define DD    256
#define KST   8
#define CDN   1024
#define NROWS 32768          // B*S
#define ROWS  32             // rows (tokens) per block
#define NT    512            // codeword tile per sweep (2 tiles per stage)
#define KC    4              // k-chunk staged in LDS (double-buffered)
#define NCH   (DD / KC)      // 64 chunks per jb tile
#define TCH   (2 * NCH)      // 128 chunks per stage
#define AST   32             // a_t row stride (bank-perfect for sumsq/update)
#define BST   256            // b tile col stride per 256-col half

__device__ __forceinline__ bool better(float a, int ja, float b, int jb_) {
    return (a < b) || (a == b && ja < jb_);
}

// ---------------------------------------------------------------------------
// numpy AVX512 pairwise sum-of-squares over 256 values (bit-emulated):
// two 128-blocks; per block 8 vectors of 16 lanes, per-lane tree
// ((v0+v1)+(v2+v3))+((v4+v5)+(v6+v7)), then _mm512_reduce_add halving tree,
// then block0+block1. All roundings explicit.
template <typename F>
__device__ __forceinline__ float np_sumsq_256(F ld) {
    float Sv = 0.f;
#pragma unroll
    for (int blk = 0; blk < 2; ++blk) {
        const int o = blk * 128;
        float w[16];
#pragma unroll
        for (int l = 0; l < 16; ++l) {
            float v[8];
#pragma unroll
            for (int j = 0; j < 8; ++j) {
                float xv = ld(o + 16 * j + l);
                v[j] = __fmul_rn(xv, xv);
            }
            float a01 = __fadd_rn(v[0], v[1]);
            float a23 = __fadd_rn(v[2], v[3]);
            float a45 = __fadd_rn(v[4], v[5]);
            float a67 = __fadd_rn(v[6], v[7]);
            w[l] = __fadd_rn(__fadd_rn(a01, a23), __fadd_rn(a45, a67));
        }
        float t8[8];
#pragma unroll
        for (int l = 0; l < 8; ++l) t8[l] = __fadd_rn(w[l], w[l + 8]);
        float t4[4];
#pragma unroll
        for (int l = 0; l < 4; ++l) t4[l] = __fadd_rn(t8[l], t8[l + 4]);
        float t2_0 = __fadd_rn(t4[0], t4[2]);
        float t2_1 = __fadd_rn(t4[1], t4[3]);
        float bs = __fadd_rn(t2_0, t2_1);
        Sv = (blk == 0) ? bs : __fadd_rn(Sv, bs);
    }
    return Sv;
}

// ---------------------------------------------------------------------------
__global__ __launch_bounds__(256) void norms_kernel(const float* __restrict__ cb,
                                                    float* __restrict__ n32) {
    int j = blockIdx.x * 256 + threadIdx.x;   // 0..8191
    const float* p = cb + (size_t)j * DD;
    n32[j] = np_sumsq_256([&](int i) { return p[i]; });
}

// ---------------------------------------------------------------------------
// Stage one codeword's 4 k-values (one float4) into the transposed B tile.
// j in 0..511 within tile; half h = j>>8, column jj = j&255.
// Store banks: (row*256 + jj) % 32 == jj % 32 -> per-wave 2-way only (free).
__device__ __forceinline__ void st_chunk(float (*bb)[KC][BST], int j, float4 v) {
    int h = j >> 8, jj = j & 255;
    bb[h][0][jj] = v.x;
    bb[h][1][jj] = v.y;
    bb[h][2][jj] = v.z;
    bb[h][3][jj] = v.w;
}

// ---------------------------------------------------------------------------
// Fused RVQ — numpy-fp32 emulation, restructured for LDS-bandwidth balance:
// 8x8 register tile per thread (0.5 B/FLOP == machine balance, was 1.25),
// NT=512 sweep in two 256-col halves (contiguous conflict-free ds_read_b128),
// KC=4 double-buffered staging (one barrier per chunk, loads a chunk ahead).
// Per-(row,col) dot chain stays single-accumulator FMA with k ascending ->
// scores bit-identical to the previous passing kernel.
__global__ __launch_bounds__(256, 3) void rvq_kernel(const float* __restrict__ x,
                                                     const float* __restrict__ cbs,
                                                     const float* __restrict__ n32,
                                                     float* __restrict__ out) {
    __shared__ __align__(16) float a_t[DD][AST];       // residual, transposed
    __shared__ __align__(16) float btb[2][2][KC][BST]; // dbuf x half x k x col
    __shared__ float rowS[ROWS];                       // np sum(res*res) per row
    __shared__ int   idxhist[KST][ROWS];               // chosen index per stage
    __shared__ float wred[4];

    const int tid  = threadIdx.x;
    const int base = blockIdx.x * ROWS;
    const int tx   = tid & 63;            // col-group: cols {h*256 + tx*4 + c}
    const int ty   = tid >> 6;            // wave id = row-group (8 rows)
    const int row0 = ty * 8;
    const int urow = tid & 31;            // update row
    const int ug   = tid >> 5;            // owned 32-dim segment

    for (int i = tid; i < ROWS * DD / 4; i += 256) {
        int row = i >> 6;
        int dq  = i & 63;
        float4 v = ((const float4*)(x + (size_t)(base + row) * DD))[dq];
        int d = dq * 4;
        a_t[d + 0][row] = v.x; a_t[d + 1][row] = v.y;
        a_t[d + 2][row] = v.z; a_t[d + 3][row] = v.w;
    }

    float loss_acc = 0.f;

    for (int s = 0; s < KST; ++s) {
        const float* cb = cbs + (size_t)s * CDN * DD;
        const float* nr = n32 + s * CDN;
        __syncthreads();                  // a_t ready (init load / prev update)

        // np-AVX512 S = sum(res*res) per row; one thread per row.
        // AST=32: bank = row -> conflict-free.
        if (tid < ROWS) {
            int row = tid;
            rowS[row] = np_sumsq_256([&](int i) { return a_t[i][row]; });
        }
        __syncthreads();

        float rb[8]; int rjx[8];
#pragma unroll
        for (int r = 0; r < 8; ++r) { rb[r] = 3.4e38f; rjx[r] = 0x7ffffff; }
        float acc[8][8];
        float4 nx0, nx1;
        const int j0 = tid, j1 = tid + 256;   // codeword slots this thread stages

        // prestore chunk 0 into buffer 0
        nx0 = *(const float4*)(cb + (size_t)j0 * DD);
        nx1 = *(const float4*)(cb + (size_t)j1 * DD);
        st_chunk(btb[0], j0, nx0);
        st_chunk(btb[0], j1, nx1);

        for (int t = 0; t < TCH; ++t) {
            const int buf = t & 1;
            if (t + 1 < TCH) {            // prefetch next chunk (global->regs)
                int jb2 = ((t + 1) >> 6) * NT, kk2 = ((t + 1) & 63) * KC;
                nx0 = *(const float4*)(cb + (size_t)(jb2 + j0) * DD + kk2);
                nx1 = *(const float4*)(cb + (size_t)(jb2 + j1) * DD + kk2);
            }
            __syncthreads();              // btb[buf] writes (from iter t-1) visible

            const int jb = (t >> 6) * NT, kk = (t & 63) * KC;
            if ((t & 63) == 0) {
#pragma unroll
                for (int r = 0; r < 8; ++r)
#pragma unroll
                    for (int c = 0; c < 8; ++c) acc[r][c] = 0.f;
            }
            const float (*b0p)[BST] = btb[buf][0];
            const float (*b1p)[BST] = btb[buf][1];
#pragma unroll
            for (int k = 0; k < KC; ++k) {
                // A: wave-uniform 16B reads (all 64 lanes same address)
                float4 a0 = *(const float4*)&a_t[kk + k][row0];
                float4 a1 = *(const float4*)&a_t[kk + k][row0 + 4];
                // B: lanes 0..63 read contiguous 1KB -> conflict-free b128
                float4 b0 = *(const float4*)&b0p[k][tx * 4];
                float4 b1 = *(const float4*)&b1p[k][tx * 4];
                float av[8] = {a0.x, a0.y, a0.z, a0.w, a1.x, a1.y, a1.z, a1.w};
                float bw[8] = {b0.x, b0.y, b0.z, b0.w, b1.x, b1.y, b1.z, b1.w};
#pragma unroll
                for (int r = 0; r < 8; ++r)
#pragma unroll
                    for (int c = 0; c < 8; ++c)
                        acc[r][c] = __builtin_fmaf(av[r], bw[c], acc[r][c]);
            }
            if (t + 1 < TCH) {            // stage prefetched chunk into other buffer
                st_chunk(btb[buf ^ 1], j0, nx0);
                st_chunk(btb[buf ^ 1], j1, nx1);
            }
            if ((t & 63) == 63) {         // np-composed score + argmin for this jb
                float nrv[2][4];
#pragma unroll
                for (int h = 0; h < 2; ++h)
#pragma unroll
                    for (int c = 0; c < 4; ++c)
                        nrv[h][c] = nr[jb + h * 256 + tx * 4 + c];
#pragma unroll
                for (int r = 0; r < 8; ++r) {
                    float Srow = rowS[row0 + r];
                    float t1 = 3.4e38f; int u1 = 0x7ffffff;
#pragma unroll
                    for (int h = 0; h < 2; ++h)
#pragma unroll
                        for (int c = 0; c < 4; ++c) {
                            int j = jb + h * 256 + tx * 4 + c;
                            float m2 = __fmul_rn(2.f, acc[r][h * 4 + c]);
                            float sc = __fadd_rn(__fsub_rn(Srow, m2), nrv[h][c]);
                            if (better(sc, j, t1, u1)) { t1 = sc; u1 = j; }
                        }
#pragma unroll
                    for (int off = 32; off >= 1; off >>= 1) {
                        float ob = __shfl_xor(t1, off, 64);
                        int   oj = __shfl_xor(u1, off, 64);
                        if (better(ob, oj, t1, u1)) { t1 = ob; u1 = oj; }
                    }
                    if (tx == 0 && better(t1, u1, rb[r], rjx[r])) { rb[r] = t1; rjx[r] = u1; }
                }
            }
        }
        if (tx == 0) {
#pragma unroll
            for (int r = 0; r < 8; ++r) idxhist[s][row0 + r] = rjx[r];
        }
        __syncthreads();

        // residual update + loss (elementwise fp32; banks 2-way via remap)
        {
            int bi = idxhist[s][urow];
            const float4* cp = (const float4*)(cb + (size_t)bi * DD + ug * 32);
#pragma unroll
            for (int dq = 0; dq < 8; ++dq) {
                float4 v = cp[dq];
                int d = ug * 32 + dq * 4;
                float e0 = __fsub_rn(a_t[d + 0][urow], v.x); a_t[d + 0][urow] = e0;
                float e1 = __fsub_rn(a_t[d + 1][urow], v.y); a_t[d + 1][urow] = e1;
                float e2 = __fsub_rn(a_t[d + 2][urow], v.z); a_t[d + 2][urow] = e2;
                float e3 = __fsub_rn(a_t[d + 3][urow], v.w); a_t[d + 3][urow] = e3;
                loss_acc += e0 * e0 + e1 * e1 + e2 * e2 + e3 * e3;
            }
        }
    }
    __syncthreads();

    // ---- outputs ----
    {
        int row = tid >> 3, s2 = tid & 7;
        out[2 + (size_t)(base + row) * KST + s2] = (float)idxhist[s2][row];
    }
    float* q = out + 2 + (size_t)NROWS * KST;
    for (int i = tid; i < ROWS * DD / 4; i += 256) {
        int row = i >> 6, dq = i & 63, d = dq * 4;
        float4 xv = ((const float4*)(x + (size_t)(base + row) * DD))[dq];
        float4 o;
        o.x = xv.x - a_t[d + 0][row];
        o.y = xv.y - a_t[d + 1][row];
        o.z = xv.z - a_t[d + 2][row];
        o.w = xv.w - a_t[d + 3][row];
        ((float4*)(q + (size_t)(base + row) * DD))[dq] = o;
    }
#pragma unroll
    for (int off = 32; off >= 1; off >>= 1) loss_acc += __shfl_down(loss_acc, off, 64);
    if ((tid & 63) == 0) wred[tid >> 6] = loss_acc;
    __syncthreads();
    if (tid == 0) {
        float t = wred[0] + wred[1] + wred[2] + wred[3];
        t *= (1.f / ((float)NROWS * (float)DD));
        atomicAdd(out + 0, t);
        atomicAdd(out + 1, t);
    }
}

// ---------------------------------------------------------------------------
extern "C" void kernel_launch(void* const* d_in, const int* in_sizes, int n_in,
                              void* d_out, int out_size, void* d_ws, size_t ws_size,
                              hipStream_t stream) {
    const float* x   = (const float*)d_in[0];   // [16,2048,256] fp32
    const float* cbs = (const float*)d_in[1];   // [8,1024,256] fp32
    float* out = (float*)d_out;
    float* n32 = (float*)d_ws;                  // 8192 floats

    hipMemsetAsync(d_out, 0, 2 * sizeof(float), stream);
    norms_kernel<<<32, 256, 0, stream>>>(cbs, n32);
    rvq_kernel<<<NROWS / ROWS, 256, 0, stream>>>(x, cbs, n32, out);
}